// Round 8
// baseline (24.907 us; speedup 1.0000x reference)
//
#include <hip/hip_runtime.h>

// Tropical (max-times) matmul: out[i,k] = max_j sigmoid(A[j,k]) * x[i,j]
// x: [2048, 256] f32   A: [256, 512] f32   out: [2048, 512] f32
//
// Round 8: W staged in LDS once per block (kills the L1-capacity-miss storm
// that R6/R7 shared: each wave was re-streaming a 64KB W slab through a
// 32KB L1 -> ~512KB/CU of line fills). Now W enters the CU once per block
// (128KB/CU), and per-lane W reads are conflict-free ds_read_b128.
//  - block = 16 i x 128 k, 4 waves (wave = 4 i x 128 k), lane owns k, k+64.
//  - Wl[k_local][pair] row stride 132 h2v (16B aligned, bank-even).
//  - xl[i_local][pair] same stride; uniform-address b128 broadcasts.
//  - no barriers in main loop; 2 blocks/CU (148.5 KB LDS), 8 waves/CU.

constexpr int JD   = 256;
constexpr int KD   = 512;
constexpr int TI   = 4;     // rows per wave
constexpr int ROWS = 16;    // rows per block
constexpr int KW   = 128;   // k per block
constexpr int NCH  = 16;    // chunks of 8 pairs (16 j)
constexpr int LSTR = 132;   // LDS row stride in h2v units

typedef _Float16 h1;
typedef __attribute__((ext_vector_type(2))) _Float16 h2v;
typedef __attribute__((ext_vector_type(4))) float f4;

__device__ __forceinline__ float sigmoidf_fast(float a) {
    return 1.0f / (1.0f + __expf(-a));
}

// Wp[p][k], p = j/2: pair (j=2p, j=2p+1). [128][512] h2v = 256 KB.
__global__ __launch_bounds__(256) void wpack(const float* __restrict__ A,
                                             h2v* __restrict__ Wp) {
    const int t  = blockIdx.x * 256 + threadIdx.x;   // 0..16383
    const int p  = t >> 7;                           // 0..127
    const int kq = (t & 127) << 2;                   // 0,4,..,508
    const f4 a0 = *(const f4*)&A[(2 * p) * KD + kq];
    const f4 a1 = *(const f4*)&A[(2 * p + 1) * KD + kq];
    union { f4 v; h2v h[4]; } u;
    #pragma unroll
    for (int q = 0; q < 4; ++q)
        u.h[q] = h2v{(h1)sigmoidf_fast(a0[q]), (h1)sigmoidf_fast(a1[q])};
    *(f4*)&Wp[p * KD + kq] = u.v;
}

__global__ __launch_bounds__(256) void tropical_mm_kernel(
        const float* __restrict__ x,
        const h2v* __restrict__ Wp,
        float* __restrict__ out) {
    __shared__ h2v Wl[KW * LSTR];    // 67584 B: [k_local][pair]
    __shared__ h2v xl[ROWS * LSTR];  //  8448 B: [i_local][pair]

    const int t    = (int)threadIdx.x;
    const int lane = t & 63;
    const int wv   = __builtin_amdgcn_readfirstlane(t >> 6);  // 0..3
    const int bk   = (int)blockIdx.x & 3;     // 4 k-slabs of 128
    const int bi   = (int)blockIdx.x >> 2;    // 128 i-blocks
    const int i0   = bi * ROWS;
    const int k0   = bk * KW;

    // ---- stage x slab -> LDS as fp16 pairs ----
    {
        const int srow = t >> 4;              // 0..15
        const int c16  = t & 15;              // 16 floats each
        const float* xs = x + (i0 + srow) * JD + c16 * 16;
        f4 f0 = ((const f4*)xs)[0];
        f4 f1 = ((const f4*)xs)[1];
        f4 f2_ = ((const f4*)xs)[2];
        f4 f3 = ((const f4*)xs)[3];
        union { f4 v; h2v h[4]; } u0, u1;
        u0.h[0] = h2v{(h1)f0.x, (h1)f0.y};
        u0.h[1] = h2v{(h1)f0.z, (h1)f0.w};
        u0.h[2] = h2v{(h1)f1.x, (h1)f1.y};
        u0.h[3] = h2v{(h1)f1.z, (h1)f1.w};
        u1.h[0] = h2v{(h1)f2_.x, (h1)f2_.y};
        u1.h[1] = h2v{(h1)f2_.z, (h1)f2_.w};
        u1.h[2] = h2v{(h1)f3.x, (h1)f3.y};
        u1.h[3] = h2v{(h1)f3.z, (h1)f3.w};
        *(f4*)&xl[srow * LSTR + c16 * 8]     = u0.v;
        *(f4*)&xl[srow * LSTR + c16 * 8 + 4] = u1.v;
    }

    // ---- stage W slab -> LDS transposed: Wl[kl][p] = Wp[p][k0+kl] ----
    {
        const int kl = t & 127;               // k_local row
        const int pb = (t >> 7) * 64;         // pair-half: 0 or 64
        const h2v* src = Wp + k0 + kl;
        #pragma unroll 4
        for (int pass = 0; pass < 16; ++pass) {
            const int p0 = pb + pass * 4;
            union { f4 v; h2v h[4]; } u;
            u.h[0] = src[(p0 + 0) * KD];      // coalesced b32 (lanes = contiguous k)
            u.h[1] = src[(p0 + 1) * KD];
            u.h[2] = src[(p0 + 2) * KD];
            u.h[3] = src[(p0 + 3) * KD];
            *(f4*)&Wl[kl * LSTR + p0] = u.v;  // conflict-free b128 write
        }
    }
    __syncthreads();

    const int r0 = wv * TI;

    h2v acc[TI][2];                  // [row][k-slot: k / k+64]
    #pragma unroll
    for (int r = 0; r < TI; ++r) {
        acc[r][0] = h2v{(h1)(-65504.0f), (h1)(-65504.0f)};
        acc[r][1] = acc[r][0];
    }

    f4 XA[TI][2], XB[TI][2];
    f4 WA[2][2], WB[2][2];

    auto loadX = [&](f4 (&X)[TI][2], int c) {
        #pragma unroll
        for (int r = 0; r < TI; ++r) {
            X[r][0] = *(const f4*)&xl[(r0 + r) * LSTR + c * 8];
            X[r][1] = *(const f4*)&xl[(r0 + r) * LSTR + c * 8 + 4];
        }
    };
    auto loadW = [&](f4 (&W)[2][2], int c) {
        W[0][0] = *(const f4*)&Wl[lane * LSTR + c * 8];
        W[0][1] = *(const f4*)&Wl[lane * LSTR + c * 8 + 4];
        W[1][0] = *(const f4*)&Wl[(64 + lane) * LSTR + c * 8];
        W[1][1] = *(const f4*)&Wl[(64 + lane) * LSTR + c * 8 + 4];
    };
    auto compute = [&](const f4 (&X)[TI][2], const f4 (&W)[2][2]) {
        #pragma unroll
        for (int r = 0; r < TI; ++r) {
            #pragma unroll
            for (int hf = 0; hf < 2; ++hf) {
                union { f4 v; h2v h[4]; } ux, uw0, uw1;
                ux.v  = X[r][hf];
                uw0.v = W[0][hf];
                uw1.v = W[1][hf];
                #pragma unroll
                for (int q = 0; q < 4; ++q) {
                    acc[r][0] = __builtin_elementwise_max(acc[r][0],
                                                          ux.h[q] * uw0.h[q]);
                    acc[r][1] = __builtin_elementwise_max(acc[r][1],
                                                          ux.h[q] * uw1.h[q]);
                }
            }
        }
    };

    // ---- double-buffered main loop (no barriers) ----
    loadX(XA, 0);
    loadW(WA, 0);

    #pragma unroll 1
    for (int c = 0; c < NCH; c += 2) {
        loadX(XB, c + 1);            // NCH even: c+1 always valid
        loadW(WB, c + 1);
        compute(XA, WA);
        if (c + 2 < NCH) {
            loadX(XA, c + 2);
            loadW(WA, c + 2);
        }
        compute(XB, WB);
    }

    // ---- epilogue: fold pair halves, write f32 ----
    #pragma unroll
    for (int r = 0; r < TI; ++r) {
        const int row = (i0 + r0 + r) * KD + k0;
        out[row + lane]      = fmaxf((float)acc[r][0][0], (float)acc[r][0][1]);
        out[row + 64 + lane] = fmaxf((float)acc[r][1][0], (float)acc[r][1][1]);
    }
}

extern "C" void kernel_launch(void* const* d_in, const int* in_sizes, int n_in,
                              void* d_out, int out_size, void* d_ws, size_t ws_size,
                              hipStream_t stream) {
    const float* x = (const float*)d_in[0];
    const float* A = (const float*)d_in[1];
    float* out = (float*)d_out;
    h2v* Wp = (h2v*)d_ws;   // 256 KB scratch

    hipLaunchKernelGGL(wpack, dim3(64), dim3(256), 0, stream, A, Wp);

    // 512 blocks: (i-block 0..127) x (k-slab 0..3), 4 waves/block
    hipLaunchKernelGGL(tropical_mm_kernel, dim3(512), dim3(256), 0, stream,
                       x, Wp, out);
}

// Round 9
// 24.002 us; speedup vs baseline: 1.0377x; 1.0377x over previous
//
#include <hip/hip_runtime.h>

// Tropical (max-times) matmul: out[i,k] = max_j sigmoid(A[j,k]) * x[i,j]
// x: [2048, 256] f32   A: [256, 512] f32   out: [2048, 512] f32
//
// Round 9: persistent-W-in-VGPR + x-through-SGPR.
// Insight from R6-R8 null results: ANY path that materializes a broadcast
// x value in a VGPR costs 64 lanes x width of RF writes (LDS return bus,
// same-addr VMEM, staging all hit the same wall). Only the SGPR file holds
// a wave-uniform value at 4B. So:
//  - lane owns one k column; W[j][k] (fp16 pairs) persistent in 64 VGPRs
//    per j-half (loaded twice, never re-streamed);
//  - x pre-packed to fp16 pairs; main kernel s_loads 32-dword chunks into
//    a 2x32-SGPR ping-pong (fits ~102 SGPR budget, unlike R2's 256);
//  - inner loop: v_pk_mul_f16 (SGPR x-operand, VGPR w) + v_pk_max_f16;
//    no LDS, no barriers. 4096 waves (4/SIMD) absorb the per-chunk
//    lgkmcnt(0) drain. VALU floor ~3.4us.

typedef _Float16 h1;
typedef __attribute__((ext_vector_type(2))) _Float16 h2v;
typedef __attribute__((ext_vector_type(4))) float f4;
typedef __attribute__((ext_vector_type(8))) unsigned int u8v;

constexpr int JD = 256;
constexpr int KD = 512;

__device__ __forceinline__ float sigmoidf_fast(float a) {
    return 1.0f / (1.0f + __expf(-a));
}

__device__ __forceinline__ h2v asH2(unsigned int u) {
    union { unsigned int x; h2v h; } c; c.x = u; return c.h;
}

// ---- pre-pack: Wp[p][k] = (sig A[2p][k], sig A[2p+1][k]) as h2v [128][512]
//      xp[row][pd]  = (x[row][2pd], x[row][2pd+1]) as dword  [2048][128]
__global__ __launch_bounds__(256) void prepack(const float* __restrict__ x,
                                               const float* __restrict__ A,
                                               h2v* __restrict__ Wp,
                                               unsigned int* __restrict__ xp) {
    const int b = (int)blockIdx.x;
    if (b < 64) {   // W part: 16384 threads
        const int t  = b * 256 + (int)threadIdx.x;
        const int p  = t >> 7;
        const int kq = (t & 127) << 2;
        const f4 a0 = *(const f4*)&A[(2 * p) * KD + kq];
        const f4 a1 = *(const f4*)&A[(2 * p + 1) * KD + kq];
        union { f4 v; h2v h[4]; } u;
        #pragma unroll
        for (int q = 0; q < 4; ++q)
            u.h[q] = h2v{(h1)sigmoidf_fast(a0[q]), (h1)sigmoidf_fast(a1[q])};
        *(f4*)&Wp[p * KD + kq] = u.v;
    } else {        // x part: 65536 threads, 8 floats -> 4 dwords each
        const int g = (b - 64) * 256 + (int)threadIdx.x;
        const f4 x0 = *(const f4*)&x[g * 8];
        const f4 x1 = *(const f4*)&x[g * 8 + 4];
        union { f4 v; h2v h[4]; } u;
        u.h[0] = h2v{(h1)x0.x, (h1)x0.y};
        u.h[1] = h2v{(h1)x0.z, (h1)x0.w};
        u.h[2] = h2v{(h1)x1.x, (h1)x1.y};
        u.h[3] = h2v{(h1)x1.z, (h1)x1.w};
        *(f4*)&xp[g * 4] = u.v;
    }
}

struct Chunk { u8v v0, v1, v2, v3; };   // 32 dwords = 64 j (uniform -> SGPRs)

__device__ __forceinline__ void loadc(Chunk& C, const unsigned int* p) {
    C.v0 = *(const u8v*)(p);
    C.v1 = *(const u8v*)(p + 8);
    C.v2 = *(const u8v*)(p + 16);
    C.v3 = *(const u8v*)(p + 24);
}

__device__ __forceinline__ void compc(const Chunk& C, const h2v* wr, h2v& acc) {
    #pragma unroll
    for (int q = 0; q < 8; ++q) {
        acc = __builtin_elementwise_max(acc, asH2(C.v0[q]) * wr[q]);
        acc = __builtin_elementwise_max(acc, asH2(C.v1[q]) * wr[8 + q]);
        acc = __builtin_elementwise_max(acc, asH2(C.v2[q]) * wr[16 + q]);
        acc = __builtin_elementwise_max(acc, asH2(C.v3[q]) * wr[24 + q]);
    }
}

__global__ __launch_bounds__(256) void tropical_mm_kernel(
        const unsigned int* __restrict__ xp,
        const h2v* __restrict__ Wp,
        float* __restrict__ out) {
    const int lane = (int)threadIdx.x & 63;
    const int wv   = __builtin_amdgcn_readfirstlane((int)threadIdx.x >> 6);
    const int slab = (int)blockIdx.x & 7;     // k-slab (shared by block -> W L1 hits)
    const int rg   = (int)blockIdx.x >> 3;    // 0..127
    const int row0 = rg * 16 + wv * 4;        // this wave's 4 rows
    const int k    = slab * 64 + lane;        // per-lane k column

    const unsigned int* xrow = xp + row0 * 128;   // uniform base

    h2v a0 = h2v{(h1)(-65504.0f), (h1)(-65504.0f)};
    h2v a1 = a0, a2 = a0, a3 = a0;

    Chunk A, B;

    #pragma unroll
    for (int H = 0; H < 2; ++H) {
        // W half: 64 persistent VGPR pairs (coalesced dword loads, L1/L2-hot)
        h2v wreg[64];
        #pragma unroll
        for (int p = 0; p < 64; ++p) wreg[p] = Wp[(H * 64 + p) * KD + k];

        const unsigned int* xb = xrow + H * 64;

        // 8 chunk-steps (4 rows x 2 chunks), 2-deep SGPR ping-pong
        loadc(A, xb);
        loadc(B, xb + 32);        compc(A, wreg,      a0);
        loadc(A, xb + 128);       compc(B, wreg + 32, a0);
        loadc(B, xb + 128 + 32);  compc(A, wreg,      a1);
        loadc(A, xb + 256);       compc(B, wreg + 32, a1);
        loadc(B, xb + 256 + 32);  compc(A, wreg,      a2);
        loadc(A, xb + 384);       compc(B, wreg + 32, a2);
        loadc(B, xb + 384 + 32);  compc(A, wreg,      a3);
                                  compc(B, wreg + 32, a3);
    }

    // fold pair halves, store f32 (coalesced dword per row)
    out[(row0 + 0) * KD + k] = fmaxf((float)a0[0], (float)a0[1]);
    out[(row0 + 1) * KD + k] = fmaxf((float)a1[0], (float)a1[1]);
    out[(row0 + 2) * KD + k] = fmaxf((float)a2[0], (float)a2[1]);
    out[(row0 + 3) * KD + k] = fmaxf((float)a3[0], (float)a3[1]);
}

extern "C" void kernel_launch(void* const* d_in, const int* in_sizes, int n_in,
                              void* d_out, int out_size, void* d_ws, size_t ws_size,
                              hipStream_t stream) {
    const float* x = (const float*)d_in[0];
    const float* A = (const float*)d_in[1];
    float* out = (float*)d_out;

    h2v* Wp = (h2v*)d_ws;                                    // 256 KB
    unsigned int* xp = (unsigned int*)((char*)d_ws + 256 * 1024);  // 1 MB

    hipLaunchKernelGGL(prepack, dim3(320), dim3(256), 0, stream, x, A, Wp, xp);

    // 1024 blocks: (rowgroup 0..127) x (slab 0..7); 4 waves/block, 4 rows/wave
    hipLaunchKernelGGL(tropical_mm_kernel, dim3(1024), dim3(256), 0, stream,
                       xp, Wp, out);
}

// Round 10
// 23.149 us; speedup vs baseline: 1.0759x; 1.0368x over previous
//
#include <hip/hip_runtime.h>

// Tropical (max-times) matmul: out[i,k] = max_j sigmoid(A[j,k]) * x[i,j]
// x: [2048, 256] f32   A: [256, 512] f32   out: [2048, 512] f32
//
// Round 10: SINGLE fused dispatch. R6-R9 (four disjoint operand-delivery
// structures) all landed 23-25us => the main loop wasn't dominant; the
// 2-dispatch + d_ws round-trip fixed cost (~8us/dispatch) was. Fusing:
//  - block = 32 i x 64 k, 256 thr (4 waves x 8 rows), grid 512 (2/CU).
//  - Phase 1: stage x slab (32x256 -> fp16 pairs, 16.9KB) and W slab
//    (sigmoid(A) on the fly, 64k x 128 pairs, 33.8KB) into LDS. The tall
//    block shape keeps sigmoid redundancy to 64 per thread (~15% VALU).
//  - Phase 2 (after ONE barrier): barrier-free fp16 ping-pong loop,
//    v_pk_mul_f16 + v_pk_max_f16, x via uniform-address b128 broadcast,
//    W via per-lane b128 (stride 132 h2v -> 4-way worst-case, cheap).

typedef _Float16 h1;
typedef __attribute__((ext_vector_type(2))) _Float16 h2v;
typedef __attribute__((ext_vector_type(4))) float f4;

constexpr int JD   = 256;
constexpr int KD   = 512;
constexpr int BI   = 32;    // rows per block
constexpr int KW   = 64;    // k per block
constexpr int TI   = 8;     // rows per wave
constexpr int LSTR = 132;   // LDS row stride in h2v (528B, 16B-aligned)
constexpr int NCH  = 16;    // chunks of 8 pairs (16 j)

__device__ __forceinline__ float sigmoidf_fast(float a) {
    return 1.0f / (1.0f + __expf(-a));
}

__global__ __launch_bounds__(256) void tropical_fused(
        const float* __restrict__ x,
        const float* __restrict__ A,
        float* __restrict__ out) {
    __shared__ h2v xl[BI * LSTR];   // 16896 B: [row][pair]
    __shared__ h2v Wl[KW * LSTR];   // 33792 B: [k_local][pair]

    const int t  = (int)threadIdx.x;
    const int kg = (int)blockIdx.x & 7;    // 8 k-groups of 64
    const int ib = (int)blockIdx.x >> 3;   // 64 i-blocks of 32
    const int i0 = ib * BI;
    const int k0 = kg * KW;

    // ---- phase 1a: stage x slab -> fp16 pairs ----
    {
        const int srow = t >> 3;           // 0..31
        const int c0   = (t & 7) * 32;     // float col base
        const float* xs = x + (i0 + srow) * JD + c0;
        #pragma unroll
        for (int q = 0; q < 4; ++q) {      // 8 floats -> 4 h2v -> 1 b128 each
            const f4 v0 = ((const f4*)xs)[2 * q];
            const f4 v1 = ((const f4*)xs)[2 * q + 1];
            union { f4 v; h2v h[4]; } u;
            u.h[0] = h2v{(h1)v0.x, (h1)v0.y};
            u.h[1] = h2v{(h1)v0.z, (h1)v0.w};
            u.h[2] = h2v{(h1)v1.x, (h1)v1.y};
            u.h[3] = h2v{(h1)v1.z, (h1)v1.w};
            *(f4*)&xl[srow * LSTR + c0 / 2 + q * 4] = u.v;
        }
    }

    // ---- phase 1b: stage W slab, sigmoid on the fly ----
    {
        const int kl = t & 63;             // k_local
        const int j0 = (t >> 6) * 64;      // 4 thread-groups x 64 j
        const float* Ak = A + k0 + kl;
        #pragma unroll 1
        for (int pass = 0; pass < 4; ++pass) {
            const int jb = j0 + pass * 16;
            float s[16];
            #pragma unroll
            for (int m = 0; m < 16; ++m)   // coalesced dword loads
                s[m] = Ak[(jb + m) * KD];
            union { f4 v; h2v h[4]; } u0, u1;
            #pragma unroll
            for (int m = 0; m < 4; ++m)
                u0.h[m] = h2v{(h1)sigmoidf_fast(s[2 * m]),
                              (h1)sigmoidf_fast(s[2 * m + 1])};
            #pragma unroll
            for (int m = 0; m < 4; ++m)
                u1.h[m] = h2v{(h1)sigmoidf_fast(s[8 + 2 * m]),
                              (h1)sigmoidf_fast(s[9 + 2 * m])};
            *(f4*)&Wl[kl * LSTR + jb / 2]     = u0.v;
            *(f4*)&Wl[kl * LSTR + jb / 2 + 4] = u1.v;
        }
    }
    __syncthreads();

    // ---- phase 2: barrier-free ping-pong compute ----
    const int lane = t & 63;
    const int wv   = __builtin_amdgcn_readfirstlane(t >> 6);
    const int r0   = wv * TI;

    h2v acc[TI];
    #pragma unroll
    for (int r = 0; r < TI; ++r)
        acc[r] = h2v{(h1)(-65504.0f), (h1)(-65504.0f)};

    f4 XA[TI][2], XB[TI][2];
    f4 WA[2], WB[2];

    auto loadX = [&](f4 (&X)[TI][2], int c) {
        #pragma unroll
        for (int r = 0; r < TI; ++r) {
            X[r][0] = *(const f4*)&xl[(r0 + r) * LSTR + c * 8];
            X[r][1] = *(const f4*)&xl[(r0 + r) * LSTR + c * 8 + 4];
        }
    };
    auto loadW = [&](f4 (&W)[2], int c) {
        W[0] = *(const f4*)&Wl[lane * LSTR + c * 8];
        W[1] = *(const f4*)&Wl[lane * LSTR + c * 8 + 4];
    };
    auto compute = [&](const f4 (&X)[TI][2], const f4 (&W)[2]) {
        #pragma unroll
        for (int r = 0; r < TI; ++r) {
            #pragma unroll
            for (int hf = 0; hf < 2; ++hf) {
                union { f4 v; h2v h[4]; } ux, uw;
                ux.v = X[r][hf];
                uw.v = W[hf];
                #pragma unroll
                for (int q = 0; q < 4; ++q)
                    acc[r] = __builtin_elementwise_max(acc[r],
                                                       ux.h[q] * uw.h[q]);
            }
        }
    };

    loadX(XA, 0);
    loadW(WA, 0);

    #pragma unroll 1
    for (int c = 0; c < NCH; c += 2) {
        loadX(XB, c + 1);              // NCH even: c+1 always valid
        loadW(WB, c + 1);
        compute(XA, WA);
        if (c + 2 < NCH) {
            loadX(XA, c + 2);
            loadW(WA, c + 2);
        }
        compute(XB, WB);
    }

    // ---- epilogue: fold pair halves, coalesced f32 stores ----
    #pragma unroll
    for (int r = 0; r < TI; ++r)
        out[(i0 + r0 + r) * KD + k0 + lane] =
            fmaxf((float)acc[r][0], (float)acc[r][1]);
}

extern "C" void kernel_launch(void* const* d_in, const int* in_sizes, int n_in,
                              void* d_out, int out_size, void* d_ws, size_t ws_size,
                              hipStream_t stream) {
    const float* x = (const float*)d_in[0];
    const float* A = (const float*)d_in[1];
    float* out = (float*)d_out;

    // 512 blocks: (i-block 0..63) x (k-group 0..7); 256 thr = 4 waves x 8 rows
    hipLaunchKernelGGL(tropical_fused, dim3(512), dim3(256), 0, stream,
                       x, A, out);
}